// Round 1
// baseline (23.761 us; speedup 1.0000x reference)
//
#include <hip/hip_runtime.h>

// GraphAttentionLayer collapses algebraically:
//   a[i,j] = s[i]  (constant over j)  =>  softmax row = uniform 1/N
//   out[i] = mean_j h[j] = (mean_j x[j]) @ W.T + b    (same for every i)
// So: column-mean of x -> 128x256 matvec -> broadcast into [8192,128] out.
// Wa/ba/adj are dead inputs.

#define N_ROWS 8192
#define F_IN   256
#define F_OUT  128
#define ROWS_PER_BLOCK 64
#define NPART  (N_ROWS / ROWS_PER_BLOCK)   // 128 partial blocks

// Kernel 1: per-block column partial sums of x, double accumulation.
// Block b sums rows [b*64, (b+1)*64); thread t owns column t.
__global__ void gat_colsum_partial(const float* __restrict__ x,
                                   double* __restrict__ part) {
    const int col = threadIdx.x;           // 0..255
    const int blk = blockIdx.x;            // 0..127
    const float* xp = x + (size_t)blk * ROWS_PER_BLOCK * F_IN + col;
    double s = 0.0;
#pragma unroll
    for (int r = 0; r < ROWS_PER_BLOCK; ++r)
        s += (double)xp[(size_t)r * F_IN];
    part[(size_t)blk * F_IN + col] = s;
}

// Kernel 2: reduce partials (fixed order -> deterministic), then m = xbar@W.T + b.
__global__ void gat_reduce_matvec(const double* __restrict__ part,
                                  const float* __restrict__ W,
                                  const float* __restrict__ b,
                                  float* __restrict__ m) {
    __shared__ double xbar[F_IN];
    const int t = threadIdx.x;             // 256 threads
    double s = 0.0;
    for (int p = 0; p < NPART; ++p)
        s += part[(size_t)p * F_IN + t];
    xbar[t] = s * (1.0 / (double)N_ROWS);
    __syncthreads();
    if (t < F_OUT) {
        double acc = (double)b[t];
        const float* wr = W + (size_t)t * F_IN;
#pragma unroll 8
        for (int k = 0; k < F_IN; ++k)
            acc += xbar[k] * (double)wr[k];
        m[t] = (float)acc;
    }
}

// Kernel 3: broadcast m into every row of out, float4 stores.
__global__ void gat_bcast(const float* __restrict__ m, float* __restrict__ out) {
    __shared__ float4 m4s[F_OUT / 4];      // 32 float4 = one row
    if (threadIdx.x < F_OUT / 4)
        m4s[threadIdx.x] = ((const float4*)m)[threadIdx.x];
    __syncthreads();
    const size_t total4 = (size_t)N_ROWS * F_OUT / 4;   // 262144
    size_t idx = (size_t)blockIdx.x * blockDim.x + threadIdx.x;
    const size_t stride = (size_t)gridDim.x * blockDim.x;
    for (; idx < total4; idx += stride)
        ((float4*)out)[idx] = m4s[idx & (F_OUT / 4 - 1)];
}

extern "C" void kernel_launch(void* const* d_in, const int* in_sizes, int n_in,
                              void* d_out, int out_size, void* d_ws, size_t ws_size,
                              hipStream_t stream) {
    const float* x = (const float*)d_in[0];   // [8192, 256]
    // d_in[1] = adj (unused)
    const float* W = (const float*)d_in[2];   // [128, 256]
    const float* b = (const float*)d_in[3];   // [128]
    // d_in[4] = Wa, d_in[5] = ba (algebraically dead)
    float* out = (float*)d_out;               // [8192, 128]

    double* part = (double*)d_ws;                                  // 128*256 doubles
    float*  m    = (float*)((char*)d_ws + (size_t)NPART * F_IN * sizeof(double));

    gat_colsum_partial<<<NPART, F_IN, 0, stream>>>(x, part);
    gat_reduce_matvec<<<1, F_IN, 0, stream>>>(part, W, b, m);
    gat_bcast<<<1024, 256, 0, stream>>>(m, out);
}